// Round 11
// baseline (495.889 us; speedup 1.0000x reference)
//
#include <hip/hip_runtime.h>
#include <stdint.h>

// Problem constants: B=4, NP=512, NC=256, E=128, C=32, NBUCKET=20.

typedef float f32x4 __attribute__((ext_vector_type(4)));
typedef short s16x8 __attribute__((ext_vector_type(8)));

#define DEV static __device__ __forceinline__

// Manual RNE bf16 convert: 3 VALU ops, NO NaN/Inf branch (inputs finite).
DEV unsigned short f2bf(float f) {
  unsigned u = __builtin_bit_cast(unsigned, f);
  u += 0x7FFFu + ((u >> 16) & 1u);   // RNE
  return (unsigned short)(u >> 16);
}
DEV float bf2f(unsigned short h) {
  unsigned u = ((unsigned)h) << 16;
  return __builtin_bit_cast(float, u);
}

// ---------------------------------------------------------------- prep ----
// Segments (grid-stride over 1,839,112 items; zmb first => 64-aligned waves
// for ballot):
//  [0,524288)          zmb: packed z_mask[b][np][nc] -> bits zmb[(b,nc)][np]
//  [524288,1048576)    WTO[e][k] = W_out[k][e] bf16
//  [1048576,1310720)   PT[b][e][np] = pocket[b][np][e] bf16
//  [1310720,1314816)   WT_LIN[c][k] = W_lin[k][c] bf16
//  [1314816,1314824)   accg zero
//  [1314824,1839112)   cdisT[b][nc][np5*32+c] = cdis[b][16c+nc/16][16(nc&15)+np5]
__global__ void prep_k(const float* __restrict__ wlin,
                       const float* __restrict__ pocket,
                       const float* __restrict__ wout,
                       const int* __restrict__ zmask,
                       const float* __restrict__ cdis,
                       unsigned short* __restrict__ wtlin,
                       unsigned short* __restrict__ pt,
                       unsigned short* __restrict__ wto,
                       unsigned long long* __restrict__ zmb,
                       float* __restrict__ cdisT,
                       float* __restrict__ accg) {
  for (int i = blockIdx.x * 256 + threadIdx.x; i < 1839112; i += gridDim.x * 256) {
    if (i < 524288) {                 // zmb ballot: i = ((b*256+nc)*512)+np
      int np = i & 511, nc = (i >> 9) & 255, b = i >> 17;
      unsigned long long bal = __ballot(zmask[b * 131072 + np * 256 + nc] != 0);
      if ((i & 63) == 0) zmb[i >> 6] = bal;
    } else if (i < 1048576) {         // WTO
      int o = i - 524288;
      int e = o >> 12, k = o & 4095;
      wto[o] = f2bf(wout[k * 128 + e]);
    } else if (i < 1310720) {         // PT
      int o = i - 1048576;
      int np = o & 511, r = o >> 9;
      int e = r & 127, b = r >> 7;
      pt[o] = f2bf(pocket[(b * 512 + np) * 128 + e]);
    } else if (i < 1314816) {         // WT_LIN
      int o = i - 1310720;
      int k = o & 127, c = o >> 7;
      wtlin[o] = f2bf(wlin[k * 32 + c]);
    } else if (i < 1314824) {
      accg[i - 1314816] = 0.0f;
    } else {                          // cdisT: o = b*131072 + nc*512 + np5*32 + c
      int o = i - 1314824;
      int c = o & 31, np5 = (o >> 5) & 15, nc = (o >> 9) & 255, b = o >> 17;
      cdisT[o] = cdis[(b * 512 + 16 * c + (nc >> 4)) * 256 + 16 * (nc & 15) + np5];
    }
  }
}

// ---------------------------------------------------------------- mega ----
// One block per (nc, b). Phase 1 loads z MFMA A-fragments DIRECTLY from
// global. R9 counters: MfmaUtil 1.7 / VALU 16.7 / HBM 10.6% / VGPR=64 with
// ~8.4MB scratch writes => unified-file squeeze at (256,4): 64 AGPR acc1 +
// 64 VGPR cap forced spills + killed load pipelining. (256,3) -> 170 regs:
// no spill, deeper phase-1 load ILP; LDS 37.7KB still allows the 3 blocks.
extern __shared__ char smem[];

__global__ __launch_bounds__(256, 3) void mega_k(
    const float* __restrict__ z, const int* __restrict__ zmask,
    const float* __restrict__ cdisT,
    const float* __restrict__ wdis, const float* __restrict__ bdis_g,
    const float* __restrict__ wE, const float* __restrict__ bE,
    const float* __restrict__ wG, const float* __restrict__ bG,
    const float* __restrict__ wEp, const float* __restrict__ bEp,
    const float* __restrict__ wGp, const float* __restrict__ bGp,
    const unsigned short* __restrict__ wtlin,
    const unsigned short* __restrict__ pt,
    const unsigned long long* __restrict__ zmb,
    unsigned short* __restrict__ lig, float* __restrict__ accg) {
  const int nc = blockIdx.x, b = blockIdx.y;
  const int t = threadIdx.x;
  const int w = t >> 6, ln = t & 63;
  const int m16 = ln & 15, q = ln >> 4;

  unsigned short* T = (unsigned short*)smem;               // [32][520]

  __shared__ float s_wd[640];                              // W_dis [20][32]
  __shared__ float s_bd[32];
  __shared__ float s_we[32], s_wg[32], s_wep[32], s_wgp[32];
  __shared__ float s_red[160];                             // [32][5]
  __shared__ float s_gmax[32], s_gsum[32];
  __shared__ unsigned long long s_mb[4][8];                // scrambled mask bits
  __shared__ float s_r8[8];

  if (t < 32) {
    s_bd[t] = bdis_g[t];
    s_we[t] = wE[t]; s_wg[t] = wG[t];
    s_wep[t] = wEp[t]; s_wgp[t] = wGp[t];
  }
  for (int i = t; i < 640; i += 256) s_wd[i] = wdis[i];
  // mask_rep[b,c,nc,np] = z_mask[c&3][2nc+np/256][np&255] (contiguous per nc)
  for (int i = t; i < 2048; i += 256) {
    int cm = i >> 9, nn = i & 511;
    unsigned long long bal = __ballot(zmask[cm * 131072 + nc * 512 + nn] != 0);
    if ((i & 63) == 0) s_mb[cm][nn >> 6] = bal;
  }

  // ---- Phase 1: zc_pre = z @ W_lin, A-frags straight from global.
  f32x4 acc1[8][2];
#pragma unroll
  for (int i = 0; i < 8; ++i) {
    acc1[i][0] = f32x4{0.f, 0.f, 0.f, 0.f};
    acc1[i][1] = f32x4{0.f, 0.f, 0.f, 0.f};
  }
  const float* zb = z + (size_t)b * 16777216 + (size_t)nc * 128;
  for (int k0 = 0; k0 < 128; k0 += 32) {
    s16x8 bf0 = *(const s16x8*)(wtlin + m16 * 128 + k0 + q * 8);
    s16x8 bf1 = *(const s16x8*)(wtlin + (16 + m16) * 128 + k0 + q * 8);
#pragma unroll
    for (int bt = 0; bt < 4; ++bt) {
      f32x4 z0[2], z1[2];
#pragma unroll
      for (int i = 0; i < 2; ++i) {
        int np = (w * 8 + bt * 2 + i) * 16 + m16;
        const float* p = zb + (size_t)np * 32768 + k0 + q * 8;
        z0[i] = *(const f32x4*)p;
        z1[i] = *(const f32x4*)(p + 4);
      }
#pragma unroll
      for (int i = 0; i < 2; ++i) {
        s16x8 af;
#pragma unroll
        for (int j = 0; j < 4; ++j) af[j] = (short)f2bf(z0[i][j]);
#pragma unroll
        for (int j = 0; j < 4; ++j) af[4 + j] = (short)f2bf(z1[i][j]);
        int ai = bt * 2 + i;
        acc1[ai][0] = __builtin_amdgcn_mfma_f32_16x16x32_bf16(af, bf0, acc1[ai][0], 0, 0, 0);
        acc1[ai][1] = __builtin_amdgcn_mfma_f32_16x16x32_bf16(af, bf1, acc1[ai][1], 0, 0, 0);
      }
    }
  }

  // ---- Phase 2: softmax over np per c. D-frag: col(c)=ln&15, row(np)=q*4+r.
  float mx[2] = {-3.0e38f, -3.0e38f};
#pragma unroll
  for (int ai = 0; ai < 8; ++ai)
#pragma unroll
    for (int ct = 0; ct < 2; ++ct)
#pragma unroll
      for (int r = 0; r < 4; ++r) mx[ct] = fmaxf(mx[ct], acc1[ai][ct][r]);
#pragma unroll
  for (int ct = 0; ct < 2; ++ct) {
    float v = mx[ct];
    v = fmaxf(v, __shfl_xor(v, 16));
    v = fmaxf(v, __shfl_xor(v, 32));
    mx[ct] = v;
  }
  if (ln < 16) { s_red[ln * 5 + w] = mx[0]; s_red[(16 + ln) * 5 + w] = mx[1]; }
  __syncthreads();
  if (t < 32)
    s_gmax[t] = fmaxf(fmaxf(s_red[t * 5], s_red[t * 5 + 1]),
                      fmaxf(s_red[t * 5 + 2], s_red[t * 5 + 3]));
  __syncthreads();
  float sm[2] = {0.f, 0.f};
#pragma unroll
  for (int ct = 0; ct < 2; ++ct) {
    float g = s_gmax[ct * 16 + m16];
#pragma unroll
    for (int ai = 0; ai < 8; ++ai)
#pragma unroll
      for (int r = 0; r < 4; ++r) {
        float e = __expf(acc1[ai][ct][r] - g);
        acc1[ai][ct][r] = e;
        sm[ct] += e;
      }
  }
#pragma unroll
  for (int ct = 0; ct < 2; ++ct) {
    float v = sm[ct];
    v += __shfl_xor(v, 16);
    v += __shfl_xor(v, 32);
    sm[ct] = v;
  }
  if (ln < 16) { s_red[ln * 5 + w] = sm[0]; s_red[(16 + ln) * 5 + w] = sm[1]; }
  __syncthreads();
  if (t < 32)
    s_gsum[t] = 1.0f / (s_red[t * 5] + s_red[t * 5 + 1] + s_red[t * 5 + 2] + s_red[t * 5 + 3]);
  __syncthreads();

  // ---- Phase 2b: scale + store T bf16 (packed 8B stores)
#pragma unroll
  for (int ct = 0; ct < 2; ++ct) {
    int c = ct * 16 + m16;
    float s = s_gsum[c];
#pragma unroll
    for (int ai = 0; ai < 8; ++ai) {
      int npb = (w * 8 + ai) * 16 + q * 4;
      unsigned lo = (unsigned)f2bf(acc1[ai][ct][0] * s) |
                    ((unsigned)f2bf(acc1[ai][ct][1] * s) << 16);
      unsigned hi = (unsigned)f2bf(acc1[ai][ct][2] * s) |
                    ((unsigned)f2bf(acc1[ai][ct][3] * s) << 16);
      *(uint2*)(T + c * 520 + npb) = make_uint2(lo, hi);
    }
  }
  __syncthreads();

  // ---- Phase 3: dis_bias (K=20 GEMM in registers) + mask, RMW into T.
  {
    const float SUSK = 8.4335794f;    // 1.14136 * e^2
    const float* cdb = cdisT + (size_t)(b * 256 + nc) * 512;
#pragma unroll
    for (int tt = 0; tt < 2; ++tt) {
      int task = t + tt * 256;
      int c = task & 31, np5 = task >> 5;
      float d = cdb[task];
      float val[32];
#pragma unroll
      for (int kk = 0; kk < 32; ++kk) val[kk] = s_bd[kk];
      for (int j = 0; j < 20; ++j) {
        float diff = d * (21.0f / 15.0f) - (float)(j + 1);
        float y1 = diff + 1.f, y2 = 1.f - diff;
        float u = 0.f;
        if (y1 > 0.f && y2 > 0.f) u = SUSK * __expf(-1.f / y1 - 1.f / y2);
#pragma unroll
        for (int kk = 0; kk < 32; ++kk) val[kk] += u * s_wd[j * 32 + kk];
      }
      int npb = np5 * 32;
      unsigned long long mw = s_mb[c & 3][npb >> 6];
#pragma unroll
      for (int kb2 = 0; kb2 < 4; ++kb2) {
        unsigned short* tp = T + c * 520 + npb + kb2 * 8;
        s16x8 tv = *(s16x8*)tp;
        s16x8 ov;
#pragma unroll
        for (int kk = 0; kk < 8; ++kk) {
          float x = bf2f((unsigned short)tv[kk]) + val[kb2 * 8 + kk];
          int mk = (int)((mw >> ((npb + kb2 * 8 + kk) & 63)) & 1ull);
          ov[kk] = (short)f2bf(mk ? 1e-9f : x);
        }
        *(s16x8*)tp = ov;
      }
    }
  }
  __syncthreads();

  // ---- Phase 4: gated energy heads; z_mask[b,np,nc] from packed zmb.
  {
    float aff = 0.f, prm = 0.f;
    const float bg0 = bG[0], be0 = bE[0], bgp0 = bGp[0], bep0 = bEp[0];
    const unsigned long long* zw = zmb + (size_t)(b * 256 + nc) * 8;
#pragma unroll
    for (int s = 0; s < 2; ++s) {
      int np = s * 256 + t;
      float g = bg0, e = be0, gp = bgp0, ep = bep0;
      for (int c = 0; c < 32; ++c) {
        float tv = bf2f(T[c * 520 + np]);
        g += tv * s_wg[c]; e += tv * s_we[c];
        gp += tv * s_wgp[c]; ep += tv * s_wep[c];
      }
      if ((zw[np >> 6] >> (np & 63)) & 1ull) {
        aff += e / (1.f + __expf(-g));
        prm += ep / (1.f + __expf(-gp));
      }
    }
#pragma unroll
    for (int d = 32; d >= 1; d >>= 1) {
      aff += __shfl_xor(aff, d);
      prm += __shfl_xor(prm, d);
    }
    if (ln == 0) { s_r8[w] = aff; s_r8[4 + w] = prm; }
    __syncthreads();
    if (t == 0) {
      atomicAdd(accg + b, s_r8[0] + s_r8[1] + s_r8[2] + s_r8[3]);
      atomicAdd(accg + 4 + b, s_r8[4] + s_r8[5] + s_r8[6] + s_r8[7]);
    }
  }

  // ---- Phase 5: lig[c,e] = sum_np T[c,np] * P[np,e] via MFMA.
  {
    f32x4 a5[2][2];
    a5[0][0] = f32x4{0.f, 0.f, 0.f, 0.f}; a5[0][1] = a5[0][0];
    a5[1][0] = a5[0][0]; a5[1][1] = a5[0][0];
    const unsigned short* ptb = pt + b * 65536;
    for (int k0 = 0; k0 < 512; k0 += 32) {
      s16x8 aT0 = *(const s16x8*)(T + m16 * 520 + k0 + q * 8);
      s16x8 aT1 = *(const s16x8*)(T + (16 + m16) * 520 + k0 + q * 8);
      s16x8 bP0 = *(const s16x8*)(ptb + (w * 32 + m16) * 512 + k0 + q * 8);
      s16x8 bP1 = *(const s16x8*)(ptb + (w * 32 + 16 + m16) * 512 + k0 + q * 8);
      a5[0][0] = __builtin_amdgcn_mfma_f32_16x16x32_bf16(aT0, bP0, a5[0][0], 0, 0, 0);
      a5[0][1] = __builtin_amdgcn_mfma_f32_16x16x32_bf16(aT0, bP1, a5[0][1], 0, 0, 0);
      a5[1][0] = __builtin_amdgcn_mfma_f32_16x16x32_bf16(aT1, bP0, a5[1][0], 0, 0, 0);
      a5[1][1] = __builtin_amdgcn_mfma_f32_16x16x32_bf16(aT1, bP1, a5[1][1], 0, 0, 0);
    }
    unsigned short* lg = lig + (size_t)(b * 256 + nc) * 4096;
#pragma unroll
    for (int mt = 0; mt < 2; ++mt)
#pragma unroll
      for (int u = 0; u < 2; ++u)
#pragma unroll
        for (int r = 0; r < 4; ++r) {
          int c = mt * 16 + q * 4 + r;
          int e = w * 32 + u * 16 + m16;
          lg[c * 128 + e] = f2bf(a5[mt][u][r]);
        }
  }
}

// ---------------------------------------------------------------- proj ----
// ligand = LIG[1024][4096] @ WTO^T, atomic-free: grid (64,2) = 128 blocks.
// Block = M=16 rows x N=64 cols; wave w owns the 16x16 N-tile at nb*64+w*16.
// Full K=4096, unroll 8. Direct stores, bias in epilogue.
__global__ __launch_bounds__(256, 4) void proj_k(
    const unsigned short* __restrict__ lig, const unsigned short* __restrict__ wto,
    const float* __restrict__ accg, const float* __restrict__ bias,
    const float* __restrict__ biasp, const float* __restrict__ bout,
    float* __restrict__ outp) {
  const int mb = blockIdx.x, nb = blockIdx.y;
  const int t = threadIdx.x, w = t >> 6, ln = t & 63;
  const int m16 = ln & 15, q = ln >> 4;
  f32x4 acc = f32x4{0.f, 0.f, 0.f, 0.f};
  const unsigned short* la = lig + (size_t)(mb * 16 + m16) * 4096 + q * 8;
  const unsigned short* wb = wto + (size_t)(nb * 64 + w * 16 + m16) * 4096 + q * 8;
#pragma unroll 8
  for (int k0 = 0; k0 < 4096; k0 += 32) {
    s16x8 af = *(const s16x8*)(la + k0);
    s16x8 bf = *(const s16x8*)(wb + k0);
    acc = __builtin_amdgcn_mfma_f32_16x16x32_bf16(af, bf, acc, 0, 0, 0);
  }
  // D-frag: row(M, from A-row) = q*4+r, col(from B-row) = m16.
  const int col = nb * 64 + w * 16 + m16;
  const float bo = bout[col];
#pragma unroll
  for (int r = 0; r < 4; ++r)
    outp[(size_t)(mb * 16 + q * 4 + r) * 128 + col] = acc[r] + bo;
  if (mb == 0 && nb == 0 && t < 8) {
    float base = (t < 4) ? bias[0] : biasp[0];
    float x = base + accg[t];
    outp[131072 + t] = (x >= 0.f) ? x : 0.01f * x;   // leaky_relu
  }
}

// -------------------------------------------------------------- launch ----
extern "C" void kernel_launch(void* const* d_in, const int* in_sizes, int n_in,
                              void* d_out, int out_size, void* d_ws, size_t ws_size,
                              hipStream_t stream) {
  const float* z      = (const float*)d_in[0];
  const int*   zmask  = (const int*)d_in[1];
  const float* pocket = (const float*)d_in[2];
  const float* cdis   = (const float*)d_in[3];
  const float* wlin   = (const float*)d_in[4];
  // d_in[5] = b_lin: cancels in softmax — unused.
  const float* wdis   = (const float*)d_in[6];
  const float* bdis   = (const float*)d_in[7];
  const float* wE     = (const float*)d_in[8];
  const float* bE     = (const float*)d_in[9];
  const float* wG     = (const float*)d_in[10];
  const float* bG     = (const float*)d_in[11];
  const float* bias   = (const float*)d_in[12];
  const float* wEp    = (const float*)d_in[13];
  const float* bEp    = (const float*)d_in[14];
  const float* wGp    = (const float*)d_in[15];
  const float* bGp    = (const float*)d_in[16];
  const float* biasp  = (const float*)d_in[17];
  const float* wout   = (const float*)d_in[18];
  const float* bout   = (const float*)d_in[19];

  char* ws = (char*)d_ws;
  float* accg                  = (float*)(ws + 0);              // 8 f
  unsigned short* wtlin        = (unsigned short*)(ws + 1024);  // 8 KB
  unsigned long long* zmb      = (unsigned long long*)(ws + 16384);   // 64 KB
  unsigned short* pt           = (unsigned short*)(ws + 131072);      // 512 KB
  float* cdisT                 = (float*)(ws + 655360);               // 2 MB
  unsigned short* wto          = (unsigned short*)(ws + 2752512);     // 1 MB
  unsigned short* lig          = (unsigned short*)(ws + 4194304);     // 8 MB
  float* outp = (float*)d_out;

  prep_k<<<1024, 256, 0, stream>>>(wlin, pocket, wout, zmask, cdis,
                                   wtlin, pt, wto, zmb, cdisT, accg);
  mega_k<<<dim3(256, 4), 256, 33280, stream>>>(z, zmask, cdisT, wdis, bdis,
      wE, bE, wG, bG, wEp, bEp, wGp, bGp, wtlin, pt, zmb, lig, accg);
  proj_k<<<dim3(64, 2), 256, 0, stream>>>(lig, wto, accg, bias, biasp, bout, outp);
}

// Round 13
// 489.882 us; speedup vs baseline: 1.0123x; 1.0123x over previous
//
#include <hip/hip_runtime.h>
#include <stdint.h>

// Problem constants: B=4, NP=512, NC=256, E=128, C=32, NBUCKET=20.

typedef float f32x4 __attribute__((ext_vector_type(4)));
typedef short s16x8 __attribute__((ext_vector_type(8)));

#define DEV static __device__ __forceinline__

// Manual RNE bf16 convert: 3 VALU ops, NO NaN/Inf branch (inputs finite).
DEV unsigned short f2bf(float f) {
  unsigned u = __builtin_bit_cast(unsigned, f);
  u += 0x7FFFu + ((u >> 16) & 1u);   // RNE
  return (unsigned short)(u >> 16);
}
DEV float bf2f(unsigned short h) {
  unsigned u = ((unsigned)h) << 16;
  return __builtin_bit_cast(float, u);
}

// ---------------------------------------------------------------- prep ----
// Segments (grid-stride over 1,839,112 items; zmb first => 64-aligned waves
// for ballot):
//  [0,524288)          zmb: packed z_mask[b][np][nc] -> bits zmb[(b,nc)][np]
//  [524288,1048576)    WTO[e][k] = W_out[k][e] bf16
//  [1048576,1310720)   PT[b][e][np] = pocket[b][np][e] bf16
//  [1310720,1314816)   WT_LIN[c][k] = W_lin[k][c] bf16
//  [1314816,1314824)   accg zero
//  [1314824,1839112)   cdisT[b][nc][np5*32+c] = cdis[b][16c+nc/16][16(nc&15)+np5]
__global__ void prep_k(const float* __restrict__ wlin,
                       const float* __restrict__ pocket,
                       const float* __restrict__ wout,
                       const int* __restrict__ zmask,
                       const float* __restrict__ cdis,
                       unsigned short* __restrict__ wtlin,
                       unsigned short* __restrict__ pt,
                       unsigned short* __restrict__ wto,
                       unsigned long long* __restrict__ zmb,
                       float* __restrict__ cdisT,
                       float* __restrict__ accg) {
  for (int i = blockIdx.x * 256 + threadIdx.x; i < 1839112; i += gridDim.x * 256) {
    if (i < 524288) {                 // zmb ballot: i = ((b*256+nc)*512)+np
      int np = i & 511, nc = (i >> 9) & 255, b = i >> 17;
      unsigned long long bal = __ballot(zmask[b * 131072 + np * 256 + nc] != 0);
      if ((i & 63) == 0) zmb[i >> 6] = bal;
    } else if (i < 1048576) {         // WTO
      int o = i - 524288;
      int e = o >> 12, k = o & 4095;
      wto[o] = f2bf(wout[k * 128 + e]);
    } else if (i < 1310720) {         // PT
      int o = i - 1048576;
      int np = o & 511, r = o >> 9;
      int e = r & 127, b = r >> 7;
      pt[o] = f2bf(pocket[(b * 512 + np) * 128 + e]);
    } else if (i < 1314816) {         // WT_LIN
      int o = i - 1310720;
      int k = o & 127, c = o >> 7;
      wtlin[o] = f2bf(wlin[k * 32 + c]);
    } else if (i < 1314824) {
      accg[i - 1314816] = 0.0f;
    } else {                          // cdisT: o = b*131072 + nc*512 + np5*32 + c
      int o = i - 1314824;
      int c = o & 31, np5 = (o >> 5) & 15, nc = (o >> 9) & 255, b = o >> 17;
      cdisT[o] = cdis[(b * 512 + 16 * c + (nc >> 4)) * 256 + 16 * (nc & 15) + np5];
    }
  }
}

// ---------------------------------------------------------------- mega ----
// One block per (nc, b). R9: (256,4) squeezed to 64 VGPR -> spills (WRITE
// 16.4MB) + ~2 loads in flight. R11: (256,3) killed spills (WRITE 8.26MB,
// exactly lig) but VGPR stayed 72 -> still ~2 loads in flight -> 898 GB/s
// (matches 12 waves x ~5 x 16B / 700cy). Fix: BATCH all 16 z-loads per k0
// into named arrays before convert+MFMA -> 16 in flight -> ~3 TB/s.
// Staging 64 + acc 64 + frags/addr ~= 150 <= 170 budget at 3 blocks/CU.
extern __shared__ char smem[];

__global__ __launch_bounds__(256, 3) void mega_k(
    const float* __restrict__ z, const int* __restrict__ zmask,
    const float* __restrict__ cdisT,
    const float* __restrict__ wdis, const float* __restrict__ bdis_g,
    const float* __restrict__ wE, const float* __restrict__ bE,
    const float* __restrict__ wG, const float* __restrict__ bG,
    const float* __restrict__ wEp, const float* __restrict__ bEp,
    const float* __restrict__ wGp, const float* __restrict__ bGp,
    const unsigned short* __restrict__ wtlin,
    const unsigned short* __restrict__ pt,
    const unsigned long long* __restrict__ zmb,
    unsigned short* __restrict__ lig, float* __restrict__ accg) {
  const int nc = blockIdx.x, b = blockIdx.y;
  const int t = threadIdx.x;
  const int w = t >> 6, ln = t & 63;
  const int m16 = ln & 15, q = ln >> 4;

  unsigned short* T = (unsigned short*)smem;               // [32][520]

  __shared__ float s_wd[640];                              // W_dis [20][32]
  __shared__ float s_bd[32];
  __shared__ float s_we[32], s_wg[32], s_wep[32], s_wgp[32];
  __shared__ float s_red[160];                             // [32][5]
  __shared__ float s_gmax[32], s_gsum[32];
  __shared__ unsigned long long s_mb[4][8];                // scrambled mask bits
  __shared__ float s_r8[8];

  if (t < 32) {
    s_bd[t] = bdis_g[t];
    s_we[t] = wE[t]; s_wg[t] = wG[t];
    s_wep[t] = wEp[t]; s_wgp[t] = wGp[t];
  }
  for (int i = t; i < 640; i += 256) s_wd[i] = wdis[i];
  // mask_rep[b,c,nc,np] = z_mask[c&3][2nc+np/256][np&255] (contiguous per nc)
  for (int i = t; i < 2048; i += 256) {
    int cm = i >> 9, nn = i & 511;
    unsigned long long bal = __ballot(zmask[cm * 131072 + nc * 512 + nn] != 0);
    if ((i & 63) == 0) s_mb[cm][nn >> 6] = bal;
  }

  // ---- Phase 1: zc_pre = z @ W_lin, A-frags straight from global.
  f32x4 acc1[8][2];
#pragma unroll
  for (int i = 0; i < 8; ++i) {
    acc1[i][0] = f32x4{0.f, 0.f, 0.f, 0.f};
    acc1[i][1] = f32x4{0.f, 0.f, 0.f, 0.f};
  }
  const float* zb = z + (size_t)b * 16777216 + (size_t)nc * 128;
  for (int k0 = 0; k0 < 128; k0 += 32) {
    s16x8 bf0 = *(const s16x8*)(wtlin + m16 * 128 + k0 + q * 8);
    s16x8 bf1 = *(const s16x8*)(wtlin + (16 + m16) * 128 + k0 + q * 8);
    // Batch ALL 16 loads first: 16 vmcnt slots in flight; per-use waitcnt
    // lets loads r+1..15 ride while r=0 is converted/MFMA'd.
    f32x4 zlo[8], zhi[8];
#pragma unroll
    for (int r = 0; r < 8; ++r) {
      int np = (w * 8 + r) * 16 + m16;
      const float* p = zb + (size_t)np * 32768 + k0 + q * 8;
      zlo[r] = *(const f32x4*)p;
      zhi[r] = *(const f32x4*)(p + 4);
    }
#pragma unroll
    for (int r = 0; r < 8; ++r) {
      s16x8 af;
#pragma unroll
      for (int j = 0; j < 4; ++j) af[j] = (short)f2bf(zlo[r][j]);
#pragma unroll
      for (int j = 0; j < 4; ++j) af[4 + j] = (short)f2bf(zhi[r][j]);
      acc1[r][0] = __builtin_amdgcn_mfma_f32_16x16x32_bf16(af, bf0, acc1[r][0], 0, 0, 0);
      acc1[r][1] = __builtin_amdgcn_mfma_f32_16x16x32_bf16(af, bf1, acc1[r][1], 0, 0, 0);
    }
  }

  // ---- Phase 2: softmax over np per c. D-frag: col(c)=ln&15, row(np)=q*4+r.
  float mx[2] = {-3.0e38f, -3.0e38f};
#pragma unroll
  for (int ai = 0; ai < 8; ++ai)
#pragma unroll
    for (int ct = 0; ct < 2; ++ct)
#pragma unroll
      for (int r = 0; r < 4; ++r) mx[ct] = fmaxf(mx[ct], acc1[ai][ct][r]);
#pragma unroll
  for (int ct = 0; ct < 2; ++ct) {
    float v = mx[ct];
    v = fmaxf(v, __shfl_xor(v, 16));
    v = fmaxf(v, __shfl_xor(v, 32));
    mx[ct] = v;
  }
  if (ln < 16) { s_red[ln * 5 + w] = mx[0]; s_red[(16 + ln) * 5 + w] = mx[1]; }
  __syncthreads();
  if (t < 32)
    s_gmax[t] = fmaxf(fmaxf(s_red[t * 5], s_red[t * 5 + 1]),
                      fmaxf(s_red[t * 5 + 2], s_red[t * 5 + 3]));
  __syncthreads();
  float sm[2] = {0.f, 0.f};
#pragma unroll
  for (int ct = 0; ct < 2; ++ct) {
    float g = s_gmax[ct * 16 + m16];
#pragma unroll
    for (int ai = 0; ai < 8; ++ai)
#pragma unroll
      for (int r = 0; r < 4; ++r) {
        float e = __expf(acc1[ai][ct][r] - g);
        acc1[ai][ct][r] = e;
        sm[ct] += e;
      }
  }
#pragma unroll
  for (int ct = 0; ct < 2; ++ct) {
    float v = sm[ct];
    v += __shfl_xor(v, 16);
    v += __shfl_xor(v, 32);
    sm[ct] = v;
  }
  if (ln < 16) { s_red[ln * 5 + w] = sm[0]; s_red[(16 + ln) * 5 + w] = sm[1]; }
  __syncthreads();
  if (t < 32)
    s_gsum[t] = 1.0f / (s_red[t * 5] + s_red[t * 5 + 1] + s_red[t * 5 + 2] + s_red[t * 5 + 3]);
  __syncthreads();

  // ---- Phase 2b: scale + store T bf16 (packed 8B stores)
#pragma unroll
  for (int ct = 0; ct < 2; ++ct) {
    int c = ct * 16 + m16;
    float s = s_gsum[c];
#pragma unroll
    for (int ai = 0; ai < 8; ++ai) {
      int npb = (w * 8 + ai) * 16 + q * 4;
      unsigned lo = (unsigned)f2bf(acc1[ai][ct][0] * s) |
                    ((unsigned)f2bf(acc1[ai][ct][1] * s) << 16);
      unsigned hi = (unsigned)f2bf(acc1[ai][ct][2] * s) |
                    ((unsigned)f2bf(acc1[ai][ct][3] * s) << 16);
      *(uint2*)(T + c * 520 + npb) = make_uint2(lo, hi);
    }
  }
  __syncthreads();

  // ---- Phase 3: dis_bias (K=20 GEMM in registers) + mask, RMW into T.
  {
    const float SUSK = 8.4335794f;    // 1.14136 * e^2
    const float* cdb = cdisT + (size_t)(b * 256 + nc) * 512;
#pragma unroll
    for (int tt = 0; tt < 2; ++tt) {
      int task = t + tt * 256;
      int c = task & 31, np5 = task >> 5;
      float d = cdb[task];
      float val[32];
#pragma unroll
      for (int kk = 0; kk < 32; ++kk) val[kk] = s_bd[kk];
      for (int j = 0; j < 20; ++j) {
        float diff = d * (21.0f / 15.0f) - (float)(j + 1);
        float y1 = diff + 1.f, y2 = 1.f - diff;
        float u = 0.f;
        if (y1 > 0.f && y2 > 0.f) u = SUSK * __expf(-1.f / y1 - 1.f / y2);
#pragma unroll
        for (int kk = 0; kk < 32; ++kk) val[kk] += u * s_wd[j * 32 + kk];
      }
      int npb = np5 * 32;
      unsigned long long mw = s_mb[c & 3][npb >> 6];
#pragma unroll
      for (int kb2 = 0; kb2 < 4; ++kb2) {
        unsigned short* tp = T + c * 520 + npb + kb2 * 8;
        s16x8 tv = *(s16x8*)tp;
        s16x8 ov;
#pragma unroll
        for (int kk = 0; kk < 8; ++kk) {
          float x = bf2f((unsigned short)tv[kk]) + val[kb2 * 8 + kk];
          int mk = (int)((mw >> ((npb + kb2 * 8 + kk) & 63)) & 1ull);
          ov[kk] = (short)f2bf(mk ? 1e-9f : x);
        }
        *(s16x8*)tp = ov;
      }
    }
  }
  __syncthreads();

  // ---- Phase 4: gated energy heads; z_mask[b,np,nc] from packed zmb.
  {
    float aff = 0.f, prm = 0.f;
    const float bg0 = bG[0], be0 = bE[0], bgp0 = bGp[0], bep0 = bEp[0];
    const unsigned long long* zw = zmb + (size_t)(b * 256 + nc) * 8;
#pragma unroll
    for (int s = 0; s < 2; ++s) {
      int np = s * 256 + t;
      float g = bg0, e = be0, gp = bgp0, ep = bep0;
      for (int c = 0; c < 32; ++c) {
        float tv = bf2f(T[c * 520 + np]);
        g += tv * s_wg[c]; e += tv * s_we[c];
        gp += tv * s_wgp[c]; ep += tv * s_wep[c];
      }
      if ((zw[np >> 6] >> (np & 63)) & 1ull) {
        aff += e / (1.f + __expf(-g));
        prm += ep / (1.f + __expf(-gp));
      }
    }
#pragma unroll
    for (int d = 32; d >= 1; d >>= 1) {
      aff += __shfl_xor(aff, d);
      prm += __shfl_xor(prm, d);
    }
    if (ln == 0) { s_r8[w] = aff; s_r8[4 + w] = prm; }
    __syncthreads();
    if (t == 0) {
      atomicAdd(accg + b, s_r8[0] + s_r8[1] + s_r8[2] + s_r8[3]);
      atomicAdd(accg + 4 + b, s_r8[4] + s_r8[5] + s_r8[6] + s_r8[7]);
    }
  }

  // ---- Phase 5: lig[c,e] = sum_np T[c,np] * P[np,e] via MFMA.
  {
    f32x4 a5[2][2];
    a5[0][0] = f32x4{0.f, 0.f, 0.f, 0.f}; a5[0][1] = a5[0][0];
    a5[1][0] = a5[0][0]; a5[1][1] = a5[0][0];
    const unsigned short* ptb = pt + b * 65536;
    for (int k0 = 0; k0 < 512; k0 += 32) {
      s16x8 aT0 = *(const s16x8*)(T + m16 * 520 + k0 + q * 8);
      s16x8 aT1 = *(const s16x8*)(T + (16 + m16) * 520 + k0 + q * 8);
      s16x8 bP0 = *(const s16x8*)(ptb + (w * 32 + m16) * 512 + k0 + q * 8);
      s16x8 bP1 = *(const s16x8*)(ptb + (w * 32 + 16 + m16) * 512 + k0 + q * 8);
      a5[0][0] = __builtin_amdgcn_mfma_f32_16x16x32_bf16(aT0, bP0, a5[0][0], 0, 0, 0);
      a5[0][1] = __builtin_amdgcn_mfma_f32_16x16x32_bf16(aT0, bP1, a5[0][1], 0, 0, 0);
      a5[1][0] = __builtin_amdgcn_mfma_f32_16x16x32_bf16(aT1, bP0, a5[1][0], 0, 0, 0);
      a5[1][1] = __builtin_amdgcn_mfma_f32_16x16x32_bf16(aT1, bP1, a5[1][1], 0, 0, 0);
    }
    unsigned short* lg = lig + (size_t)(b * 256 + nc) * 4096;
#pragma unroll
    for (int mt = 0; mt < 2; ++mt)
#pragma unroll
      for (int u = 0; u < 2; ++u)
#pragma unroll
        for (int r = 0; r < 4; ++r) {
          int c = mt * 16 + q * 4 + r;
          int e = w * 32 + u * 16 + m16;
          lg[c * 128 + e] = f2bf(a5[mt][u][r]);
        }
  }
}

// ---------------------------------------------------------------- proj ----
// ligand = LIG[1024][4096] @ WTO^T, atomic-free: grid (64,2) = 128 blocks.
// Block = M=16 rows x N=64 cols; wave w owns the 16x16 N-tile at nb*64+w*16.
// Full K=4096, unroll 8. Direct stores, bias in epilogue.
__global__ __launch_bounds__(256, 4) void proj_k(
    const unsigned short* __restrict__ lig, const unsigned short* __restrict__ wto,
    const float* __restrict__ accg, const float* __restrict__ bias,
    const float* __restrict__ biasp, const float* __restrict__ bout,
    float* __restrict__ outp) {
  const int mb = blockIdx.x, nb = blockIdx.y;
  const int t = threadIdx.x, w = t >> 6, ln = t & 63;
  const int m16 = ln & 15, q = ln >> 4;
  f32x4 acc = f32x4{0.f, 0.f, 0.f, 0.f};
  const unsigned short* la = lig + (size_t)(mb * 16 + m16) * 4096 + q * 8;
  const unsigned short* wb = wto + (size_t)(nb * 64 + w * 16 + m16) * 4096 + q * 8;
#pragma unroll 8
  for (int k0 = 0; k0 < 4096; k0 += 32) {
    s16x8 af = *(const s16x8*)(la + k0);
    s16x8 bf = *(const s16x8*)(wb + k0);
    acc = __builtin_amdgcn_mfma_f32_16x16x32_bf16(af, bf, acc, 0, 0, 0);
  }
  // D-frag: row(M, from A-row) = q*4+r, col(from B-row) = m16.
  const int col = nb * 64 + w * 16 + m16;
  const float bo = bout[col];
#pragma unroll
  for (int r = 0; r < 4; ++r)
    outp[(size_t)(mb * 16 + q * 4 + r) * 128 + col] = acc[r] + bo;
  if (mb == 0 && nb == 0 && t < 8) {
    float base = (t < 4) ? bias[0] : biasp[0];
    float x = base + accg[t];
    outp[131072 + t] = (x >= 0.f) ? x : 0.01f * x;   // leaky_relu
  }
}

// -------------------------------------------------------------- launch ----
extern "C" void kernel_launch(void* const* d_in, const int* in_sizes, int n_in,
                              void* d_out, int out_size, void* d_ws, size_t ws_size,
                              hipStream_t stream) {
  const float* z      = (const float*)d_in[0];
  const int*   zmask  = (const int*)d_in[1];
  const float* pocket = (const float*)d_in[2];
  const float* cdis   = (const float*)d_in[3];
  const float* wlin   = (const float*)d_in[4];
  // d_in[5] = b_lin: cancels in softmax — unused.
  const float* wdis   = (const float*)d_in[6];
  const float* bdis   = (const float*)d_in[7];
  const float* wE     = (const float*)d_in[8];
  const float* bE     = (const float*)d_in[9];
  const float* wG     = (const float*)d_in[10];
  const float* bG     = (const float*)d_in[11];
  const float* bias   = (const float*)d_in[12];
  const float* wEp    = (const float*)d_in[13];
  const float* bEp    = (const float*)d_in[14];
  const float* wGp    = (const float*)d_in[15];
  const float* bGp    = (const float*)d_in[16];
  const float* biasp  = (const float*)d_in[17];
  const float* wout   = (const float*)d_in[18];
  const float* bout   = (const float*)d_in[19];

  char* ws = (char*)d_ws;
  float* accg                  = (float*)(ws + 0);              // 8 f
  unsigned short* wtlin        = (unsigned short*)(ws + 1024);  // 8 KB
  unsigned long long* zmb      = (unsigned long long*)(ws + 16384);   // 64 KB
  unsigned short* pt           = (unsigned short*)(ws + 131072);      // 512 KB
  float* cdisT                 = (float*)(ws + 655360);               // 2 MB
  unsigned short* wto          = (unsigned short*)(ws + 2752512);     // 1 MB
  unsigned short* lig          = (unsigned short*)(ws + 4194304);     // 8 MB
  float* outp = (float*)d_out;

  prep_k<<<1024, 256, 0, stream>>>(wlin, pocket, wout, zmask, cdis,
                                   wtlin, pt, wto, zmb, cdisT, accg);
  mega_k<<<dim3(256, 4), 256, 33280, stream>>>(z, zmask, cdisT, wdis, bdis,
      wE, bE, wG, bG, wEp, bEp, wGp, bGp, wtlin, pt, zmb, lig, accg);
  proj_k<<<dim3(64, 2), 256, 0, stream>>>(lig, wto, accg, bias, biasp, bout, outp);
}

// Round 15
// 470.469 us; speedup vs baseline: 1.0540x; 1.0413x over previous
//
#include <hip/hip_runtime.h>
#include <stdint.h>

// Problem constants: B=4, NP=512, NC=256, E=128, C=32, NBUCKET=20.

typedef float f32x4 __attribute__((ext_vector_type(4)));
typedef short s16x8 __attribute__((ext_vector_type(8)));

#define DEV static __device__ __forceinline__

// Manual RNE bf16 convert: 3 VALU ops, NO NaN/Inf branch (inputs finite).
DEV unsigned short f2bf(float f) {
  unsigned u = __builtin_bit_cast(unsigned, f);
  u += 0x7FFFu + ((u >> 16) & 1u);   // RNE
  return (unsigned short)(u >> 16);
}
DEV float bf2f(unsigned short h) {
  unsigned u = ((unsigned)h) << 16;
  return __builtin_bit_cast(float, u);
}

// ---------------------------------------------------------------- prep ----
// Segments (grid-stride over 1,839,112 items; zmb first => 64-aligned waves
// for ballot):
//  [0,524288)          zmb: packed z_mask[b][np][nc] -> bits zmb[(b,nc)][np]
//  [524288,1048576)    WTO[e][k] = W_out[k][e] bf16
//  [1048576,1310720)   PT[b][e][np] = pocket[b][np][e] bf16
//  [1310720,1314816)   WT_LIN[c][k] = W_lin[k][c] bf16
//  [1314816,1314824)   accg zero
//  [1314824,1839112)   cdisT[b][nc][np5*32+c] = cdis[b][16c+nc/16][16(nc&15)+np5]
__global__ void prep_k(const float* __restrict__ wlin,
                       const float* __restrict__ pocket,
                       const float* __restrict__ wout,
                       const int* __restrict__ zmask,
                       const float* __restrict__ cdis,
                       unsigned short* __restrict__ wtlin,
                       unsigned short* __restrict__ pt,
                       unsigned short* __restrict__ wto,
                       unsigned long long* __restrict__ zmb,
                       float* __restrict__ cdisT,
                       float* __restrict__ accg) {
  for (int i = blockIdx.x * 256 + threadIdx.x; i < 1839112; i += gridDim.x * 256) {
    if (i < 524288) {                 // zmb ballot: i = ((b*256+nc)*512)+np
      int np = i & 511, nc = (i >> 9) & 255, b = i >> 17;
      unsigned long long bal = __ballot(zmask[b * 131072 + np * 256 + nc] != 0);
      if ((i & 63) == 0) zmb[i >> 6] = bal;
    } else if (i < 1048576) {         // WTO
      int o = i - 524288;
      int e = o >> 12, k = o & 4095;
      wto[o] = f2bf(wout[k * 128 + e]);
    } else if (i < 1310720) {         // PT
      int o = i - 1048576;
      int np = o & 511, r = o >> 9;
      int e = r & 127, b = r >> 7;
      pt[o] = f2bf(pocket[(b * 512 + np) * 128 + e]);
    } else if (i < 1314816) {         // WT_LIN
      int o = i - 1310720;
      int k = o & 127, c = o >> 7;
      wtlin[o] = f2bf(wlin[k * 32 + c]);
    } else if (i < 1314824) {
      accg[i - 1314816] = 0.0f;
    } else {                          // cdisT: o = b*131072 + nc*512 + np5*32 + c
      int o = i - 1314824;
      int c = o & 31, np5 = (o >> 5) & 15, nc = (o >> 9) & 255, b = o >> 17;
      cdisT[o] = cdis[(b * 512 + 16 * c + (nc >> 4)) * 256 + 16 * (nc & 15) + np5];
    }
  }
}

// ---------------------------------------------------------------- mega ----
// One block per (nc, b). R9: (256,4) -> 64 VGPR squeeze, spills. R11:
// (256,3) killed spills but VGPR 72 -> ~2 loads in flight -> 898 GB/s.
// R13: source-level load batching NULL — compiler re-sank loads (VGPR 68,
// 925 GB/s unchanged). R14: pin with sched_barrier(0) between the 16-load
// batch and consumption — scheduler cannot cross it, must hold 64 staging
// VGPRs; per-use vmcnt drains progressively. 64+64+~36 <= 170 @ 3 blk/CU.
extern __shared__ char smem[];

__global__ __launch_bounds__(256, 3) void mega_k(
    const float* __restrict__ z, const int* __restrict__ zmask,
    const float* __restrict__ cdisT,
    const float* __restrict__ wdis, const float* __restrict__ bdis_g,
    const float* __restrict__ wE, const float* __restrict__ bE,
    const float* __restrict__ wG, const float* __restrict__ bG,
    const float* __restrict__ wEp, const float* __restrict__ bEp,
    const float* __restrict__ wGp, const float* __restrict__ bGp,
    const unsigned short* __restrict__ wtlin,
    const unsigned short* __restrict__ pt,
    const unsigned long long* __restrict__ zmb,
    unsigned short* __restrict__ lig, float* __restrict__ accg) {
  const int nc = blockIdx.x, b = blockIdx.y;
  const int t = threadIdx.x;
  const int w = t >> 6, ln = t & 63;
  const int m16 = ln & 15, q = ln >> 4;

  unsigned short* T = (unsigned short*)smem;               // [32][520]

  __shared__ float s_wd[640];                              // W_dis [20][32]
  __shared__ float s_bd[32];
  __shared__ float s_we[32], s_wg[32], s_wep[32], s_wgp[32];
  __shared__ float s_red[160];                             // [32][5]
  __shared__ float s_gmax[32], s_gsum[32];
  __shared__ unsigned long long s_mb[4][8];                // scrambled mask bits
  __shared__ float s_r8[8];

  if (t < 32) {
    s_bd[t] = bdis_g[t];
    s_we[t] = wE[t]; s_wg[t] = wG[t];
    s_wep[t] = wEp[t]; s_wgp[t] = wGp[t];
  }
  for (int i = t; i < 640; i += 256) s_wd[i] = wdis[i];
  // mask_rep[b,c,nc,np] = z_mask[c&3][2nc+np/256][np&255] (contiguous per nc)
  for (int i = t; i < 2048; i += 256) {
    int cm = i >> 9, nn = i & 511;
    unsigned long long bal = __ballot(zmask[cm * 131072 + nc * 512 + nn] != 0);
    if ((i & 63) == 0) s_mb[cm][nn >> 6] = bal;
  }

  // ---- Phase 1: zc_pre = z @ W_lin, A-frags straight from global.
  f32x4 acc1[8][2];
#pragma unroll
  for (int i = 0; i < 8; ++i) {
    acc1[i][0] = f32x4{0.f, 0.f, 0.f, 0.f};
    acc1[i][1] = f32x4{0.f, 0.f, 0.f, 0.f};
  }
  const float* zb = z + (size_t)b * 16777216 + (size_t)nc * 128;
  for (int k0 = 0; k0 < 128; k0 += 32) {
    s16x8 bf0 = *(const s16x8*)(wtlin + m16 * 128 + k0 + q * 8);
    s16x8 bf1 = *(const s16x8*)(wtlin + (16 + m16) * 128 + k0 + q * 8);
    // Batch ALL 16 loads, then FENCE: sched_barrier(0) forbids the
    // scheduler from sinking loads to their uses (R13 showed it does
    // exactly that, keeping only ~2 in flight). After the fence the
    // per-use vmcnt(N) waits drain loads progressively: 16 in flight.
    f32x4 zlo[8], zhi[8];
#pragma unroll
    for (int r = 0; r < 8; ++r) {
      int np = (w * 8 + r) * 16 + m16;
      const float* p = zb + (size_t)np * 32768 + k0 + q * 8;
      zlo[r] = *(const f32x4*)p;
      zhi[r] = *(const f32x4*)(p + 4);
    }
    __builtin_amdgcn_sched_barrier(0);
#pragma unroll
    for (int r = 0; r < 8; ++r) {
      s16x8 af;
#pragma unroll
      for (int j = 0; j < 4; ++j) af[j] = (short)f2bf(zlo[r][j]);
#pragma unroll
      for (int j = 0; j < 4; ++j) af[4 + j] = (short)f2bf(zhi[r][j]);
      acc1[r][0] = __builtin_amdgcn_mfma_f32_16x16x32_bf16(af, bf0, acc1[r][0], 0, 0, 0);
      acc1[r][1] = __builtin_amdgcn_mfma_f32_16x16x32_bf16(af, bf1, acc1[r][1], 0, 0, 0);
    }
  }

  // ---- Phase 2: softmax over np per c. D-frag: col(c)=ln&15, row(np)=q*4+r.
  float mx[2] = {-3.0e38f, -3.0e38f};
#pragma unroll
  for (int ai = 0; ai < 8; ++ai)
#pragma unroll
    for (int ct = 0; ct < 2; ++ct)
#pragma unroll
      for (int r = 0; r < 4; ++r) mx[ct] = fmaxf(mx[ct], acc1[ai][ct][r]);
#pragma unroll
  for (int ct = 0; ct < 2; ++ct) {
    float v = mx[ct];
    v = fmaxf(v, __shfl_xor(v, 16));
    v = fmaxf(v, __shfl_xor(v, 32));
    mx[ct] = v;
  }
  if (ln < 16) { s_red[ln * 5 + w] = mx[0]; s_red[(16 + ln) * 5 + w] = mx[1]; }
  __syncthreads();
  if (t < 32)
    s_gmax[t] = fmaxf(fmaxf(s_red[t * 5], s_red[t * 5 + 1]),
                      fmaxf(s_red[t * 5 + 2], s_red[t * 5 + 3]));
  __syncthreads();
  float sm[2] = {0.f, 0.f};
#pragma unroll
  for (int ct = 0; ct < 2; ++ct) {
    float g = s_gmax[ct * 16 + m16];
#pragma unroll
    for (int ai = 0; ai < 8; ++ai)
#pragma unroll
      for (int r = 0; r < 4; ++r) {
        float e = __expf(acc1[ai][ct][r] - g);
        acc1[ai][ct][r] = e;
        sm[ct] += e;
      }
  }
#pragma unroll
  for (int ct = 0; ct < 2; ++ct) {
    float v = sm[ct];
    v += __shfl_xor(v, 16);
    v += __shfl_xor(v, 32);
    sm[ct] = v;
  }
  if (ln < 16) { s_red[ln * 5 + w] = sm[0]; s_red[(16 + ln) * 5 + w] = sm[1]; }
  __syncthreads();
  if (t < 32)
    s_gsum[t] = 1.0f / (s_red[t * 5] + s_red[t * 5 + 1] + s_red[t * 5 + 2] + s_red[t * 5 + 3]);
  __syncthreads();

  // ---- Phase 2b: scale + store T bf16 (packed 8B stores)
#pragma unroll
  for (int ct = 0; ct < 2; ++ct) {
    int c = ct * 16 + m16;
    float s = s_gsum[c];
#pragma unroll
    for (int ai = 0; ai < 8; ++ai) {
      int npb = (w * 8 + ai) * 16 + q * 4;
      unsigned lo = (unsigned)f2bf(acc1[ai][ct][0] * s) |
                    ((unsigned)f2bf(acc1[ai][ct][1] * s) << 16);
      unsigned hi = (unsigned)f2bf(acc1[ai][ct][2] * s) |
                    ((unsigned)f2bf(acc1[ai][ct][3] * s) << 16);
      *(uint2*)(T + c * 520 + npb) = make_uint2(lo, hi);
    }
  }
  __syncthreads();

  // ---- Phase 3: dis_bias (K=20 GEMM in registers) + mask, RMW into T.
  {
    const float SUSK = 8.4335794f;    // 1.14136 * e^2
    const float* cdb = cdisT + (size_t)(b * 256 + nc) * 512;
#pragma unroll
    for (int tt = 0; tt < 2; ++tt) {
      int task = t + tt * 256;
      int c = task & 31, np5 = task >> 5;
      float d = cdb[task];
      float val[32];
#pragma unroll
      for (int kk = 0; kk < 32; ++kk) val[kk] = s_bd[kk];
      for (int j = 0; j < 20; ++j) {
        float diff = d * (21.0f / 15.0f) - (float)(j + 1);
        float y1 = diff + 1.f, y2 = 1.f - diff;
        float u = 0.f;
        if (y1 > 0.f && y2 > 0.f) u = SUSK * __expf(-1.f / y1 - 1.f / y2);
#pragma unroll
        for (int kk = 0; kk < 32; ++kk) val[kk] += u * s_wd[j * 32 + kk];
      }
      int npb = np5 * 32;
      unsigned long long mw = s_mb[c & 3][npb >> 6];
#pragma unroll
      for (int kb2 = 0; kb2 < 4; ++kb2) {
        unsigned short* tp = T + c * 520 + npb + kb2 * 8;
        s16x8 tv = *(s16x8*)tp;
        s16x8 ov;
#pragma unroll
        for (int kk = 0; kk < 8; ++kk) {
          float x = bf2f((unsigned short)tv[kk]) + val[kb2 * 8 + kk];
          int mk = (int)((mw >> ((npb + kb2 * 8 + kk) & 63)) & 1ull);
          ov[kk] = (short)f2bf(mk ? 1e-9f : x);
        }
        *(s16x8*)tp = ov;
      }
    }
  }
  __syncthreads();

  // ---- Phase 4: gated energy heads; z_mask[b,np,nc] from packed zmb.
  {
    float aff = 0.f, prm = 0.f;
    const float bg0 = bG[0], be0 = bE[0], bgp0 = bGp[0], bep0 = bEp[0];
    const unsigned long long* zw = zmb + (size_t)(b * 256 + nc) * 8;
#pragma unroll
    for (int s = 0; s < 2; ++s) {
      int np = s * 256 + t;
      float g = bg0, e = be0, gp = bgp0, ep = bep0;
      for (int c = 0; c < 32; ++c) {
        float tv = bf2f(T[c * 520 + np]);
        g += tv * s_wg[c]; e += tv * s_we[c];
        gp += tv * s_wgp[c]; ep += tv * s_wep[c];
      }
      if ((zw[np >> 6] >> (np & 63)) & 1ull) {
        aff += e / (1.f + __expf(-g));
        prm += ep / (1.f + __expf(-gp));
      }
    }
#pragma unroll
    for (int d = 32; d >= 1; d >>= 1) {
      aff += __shfl_xor(aff, d);
      prm += __shfl_xor(prm, d);
    }
    if (ln == 0) { s_r8[w] = aff; s_r8[4 + w] = prm; }
    __syncthreads();
    if (t == 0) {
      atomicAdd(accg + b, s_r8[0] + s_r8[1] + s_r8[2] + s_r8[3]);
      atomicAdd(accg + 4 + b, s_r8[4] + s_r8[5] + s_r8[6] + s_r8[7]);
    }
  }

  // ---- Phase 5: lig[c,e] = sum_np T[c,np] * P[np,e] via MFMA.
  {
    f32x4 a5[2][2];
    a5[0][0] = f32x4{0.f, 0.f, 0.f, 0.f}; a5[0][1] = a5[0][0];
    a5[1][0] = a5[0][0]; a5[1][1] = a5[0][0];
    const unsigned short* ptb = pt + b * 65536;
    for (int k0 = 0; k0 < 512; k0 += 32) {
      s16x8 aT0 = *(const s16x8*)(T + m16 * 520 + k0 + q * 8);
      s16x8 aT1 = *(const s16x8*)(T + (16 + m16) * 520 + k0 + q * 8);
      s16x8 bP0 = *(const s16x8*)(ptb + (w * 32 + m16) * 512 + k0 + q * 8);
      s16x8 bP1 = *(const s16x8*)(ptb + (w * 32 + 16 + m16) * 512 + k0 + q * 8);
      a5[0][0] = __builtin_amdgcn_mfma_f32_16x16x32_bf16(aT0, bP0, a5[0][0], 0, 0, 0);
      a5[0][1] = __builtin_amdgcn_mfma_f32_16x16x32_bf16(aT0, bP1, a5[0][1], 0, 0, 0);
      a5[1][0] = __builtin_amdgcn_mfma_f32_16x16x32_bf16(aT1, bP0, a5[1][0], 0, 0, 0);
      a5[1][1] = __builtin_amdgcn_mfma_f32_16x16x32_bf16(aT1, bP1, a5[1][1], 0, 0, 0);
    }
    unsigned short* lg = lig + (size_t)(b * 256 + nc) * 4096;
#pragma unroll
    for (int mt = 0; mt < 2; ++mt)
#pragma unroll
      for (int u = 0; u < 2; ++u)
#pragma unroll
        for (int r = 0; r < 4; ++r) {
          int c = mt * 16 + q * 4 + r;
          int e = w * 32 + u * 16 + m16;
          lg[c * 128 + e] = f2bf(a5[mt][u][r]);
        }
  }
}

// ---------------------------------------------------------------- proj ----
// ligand = LIG[1024][4096] @ WTO^T, atomic-free: grid (64,2) = 128 blocks.
// Block = M=16 rows x N=64 cols; wave w owns the 16x16 N-tile at nb*64+w*16.
// Full K=4096, unroll 8. Direct stores, bias in epilogue.
__global__ __launch_bounds__(256, 4) void proj_k(
    const unsigned short* __restrict__ lig, const unsigned short* __restrict__ wto,
    const float* __restrict__ accg, const float* __restrict__ bias,
    const float* __restrict__ biasp, const float* __restrict__ bout,
    float* __restrict__ outp) {
  const int mb = blockIdx.x, nb = blockIdx.y;
  const int t = threadIdx.x, w = t >> 6, ln = t & 63;
  const int m16 = ln & 15, q = ln >> 4;
  f32x4 acc = f32x4{0.f, 0.f, 0.f, 0.f};
  const unsigned short* la = lig + (size_t)(mb * 16 + m16) * 4096 + q * 8;
  const unsigned short* wb = wto + (size_t)(nb * 64 + w * 16 + m16) * 4096 + q * 8;
#pragma unroll 8
  for (int k0 = 0; k0 < 4096; k0 += 32) {
    s16x8 af = *(const s16x8*)(la + k0);
    s16x8 bf = *(const s16x8*)(wb + k0);
    acc = __builtin_amdgcn_mfma_f32_16x16x32_bf16(af, bf, acc, 0, 0, 0);
  }
  // D-frag: row(M, from A-row) = q*4+r, col(from B-row) = m16.
  const int col = nb * 64 + w * 16 + m16;
  const float bo = bout[col];
#pragma unroll
  for (int r = 0; r < 4; ++r)
    outp[(size_t)(mb * 16 + q * 4 + r) * 128 + col] = acc[r] + bo;
  if (mb == 0 && nb == 0 && t < 8) {
    float base = (t < 4) ? bias[0] : biasp[0];
    float x = base + accg[t];
    outp[131072 + t] = (x >= 0.f) ? x : 0.01f * x;   // leaky_relu
  }
}

// -------------------------------------------------------------- launch ----
extern "C" void kernel_launch(void* const* d_in, const int* in_sizes, int n_in,
                              void* d_out, int out_size, void* d_ws, size_t ws_size,
                              hipStream_t stream) {
  const float* z      = (const float*)d_in[0];
  const int*   zmask  = (const int*)d_in[1];
  const float* pocket = (const float*)d_in[2];
  const float* cdis   = (const float*)d_in[3];
  const float* wlin   = (const float*)d_in[4];
  // d_in[5] = b_lin: cancels in softmax — unused.
  const float* wdis   = (const float*)d_in[6];
  const float* bdis   = (const float*)d_in[7];
  const float* wE     = (const float*)d_in[8];
  const float* bE     = (const float*)d_in[9];
  const float* wG     = (const float*)d_in[10];
  const float* bG     = (const float*)d_in[11];
  const float* bias   = (const float*)d_in[12];
  const float* wEp    = (const float*)d_in[13];
  const float* bEp    = (const float*)d_in[14];
  const float* wGp    = (const float*)d_in[15];
  const float* bGp    = (const float*)d_in[16];
  const float* biasp  = (const float*)d_in[17];
  const float* wout   = (const float*)d_in[18];
  const float* bout   = (const float*)d_in[19];

  char* ws = (char*)d_ws;
  float* accg                  = (float*)(ws + 0);              // 8 f
  unsigned short* wtlin        = (unsigned short*)(ws + 1024);  // 8 KB
  unsigned long long* zmb      = (unsigned long long*)(ws + 16384);   // 64 KB
  unsigned short* pt           = (unsigned short*)(ws + 131072);      // 512 KB
  float* cdisT                 = (float*)(ws + 655360);               // 2 MB
  unsigned short* wto          = (unsigned short*)(ws + 2752512);     // 1 MB
  unsigned short* lig          = (unsigned short*)(ws + 4194304);     // 8 MB
  float* outp = (float*)d_out;

  prep_k<<<1024, 256, 0, stream>>>(wlin, pocket, wout, zmask, cdis,
                                   wtlin, pt, wto, zmb, cdisT, accg);
  mega_k<<<dim3(256, 4), 256, 33280, stream>>>(z, zmask, cdisT, wdis, bdis,
      wE, bE, wG, bG, wEp, bEp, wGp, bGp, wtlin, pt, zmb, lig, accg);
  proj_k<<<dim3(64, 2), 256, 0, stream>>>(lig, wto, accg, bias, biasp, bout, outp);
}